// Round 5
// baseline (192.253 us; speedup 1.0000x reference)
//
#include <hip/hip_runtime.h>
#include <cstdint>

// PassiveLayer muon scattering, fused single kernel.
// PRNG reproduces JAX threefry2x32 bit-exactly:
//   base key = (0, 42); step key_i = threefry((0,42), (0, i))
//   zr[0][n],zr[2][n] = threefry(key_i, (n, n+2N)) words 0,1
//   zr[1][n],zr[3][n] = threefry(key_i, (N+n, 3N+n)) words 0,1
//
// Numeric-risk policy (absmax 0.20224 vs threshold 0.2025 = 2%*max|ref|):
//  - POSITION-critical ops (libm tanf, x/VSIZE voxel divide, rsqrtf->dz,
//    scalar update expression shapes) kept identical to passing R1-R4:
//    they set the voxel-flip set vs the np reference. DO NOT TOUCH.
//  - Damped z-draw path (scaled by theta0 ~0.0136 before reaching state)
//    tolerates <=1ulp changes (R2/R4-validated bit-stable absmax).
//  - R5 changes, all bit-exact or damped:
//    (a) final tanf pair deleted: z == Z_BOT bitwise for every muon at loop
//        exit (Sterbenz-exact em pullback), so dz1 == 0.0 and the snap is a
//        no-op;
//    (b) tan hoisted: preamble pair shared with iteration 0, recomputed at
//        body end only if the wave continues (same inputs -> same bits);
//    (c) mask simplified to (z > Z_BOT): z == 1.0 exactly after preamble
//        snap and never increases above it;
//    (d) damped pipeline packed into v_pk_fma_f32 via float2 ext vectors
//        (packed IEEE ops are bit-identical per element);
//    (e) erfinv chain-2 guard split into two pair-wise __any checks.

constexpr int   NSTEPS = 32;
constexpr float Z_TOP  = 1.0f;
constexpr float Z_BOT  = 0.9f;
constexpr float LW     = 10.0f;
constexpr float VSIZE  = 0.1f;
constexpr float STEP   = 0.01f;
constexpr float COEF_A = 13.6e-3f;
constexpr float COEF_B = 0.038f;

typedef float v2f __attribute__((ext_vector_type(2)));
__device__ __forceinline__ v2f splat(float s) { return (v2f){s, s}; }
__device__ __forceinline__ v2f pfma(v2f a, v2f b, v2f c) {
  return __builtin_elementwise_fma(a, b, c);
}

__host__ __device__ constexpr uint32_t rotl32c(uint32_t v, int d) {
  return (v << d) | (v >> (32 - d));
}

// JAX threefry2x32 (20 rounds, 5 key injections) — constexpr-capable.
template <typename U>
__host__ __device__ constexpr void threefry2x32(U k0, U k1, U& x0, U& x1) {
  U k2 = k0 ^ k1 ^ 0x1BD11BDAu;
  x0 += k0; x1 += k1;
#define TF_R(r) { x0 += x1; x1 = rotl32c(x1, r); x1 ^= x0; }
  TF_R(13) TF_R(15) TF_R(26) TF_R(6)
  x0 += k1; x1 += k2 + 1u;
  TF_R(17) TF_R(29) TF_R(16) TF_R(24)
  x0 += k2; x1 += k0 + 2u;
  TF_R(13) TF_R(15) TF_R(26) TF_R(6)
  x0 += k0; x1 += k1 + 3u;
  TF_R(17) TF_R(29) TF_R(16) TF_R(24)
  x0 += k1; x1 += k2 + 4u;
  TF_R(13) TF_R(15) TF_R(26) TF_R(6)
  x0 += k2; x1 += k0 + 5u;
#undef TF_R
}

// Per-step keys: fold_in(key(42), i) = threefry((0,42), (0,i)) — compile-time.
struct KeyTab { uint32_t a[NSTEPS]; uint32_t b[NSTEPS]; };
constexpr KeyTab make_keys() {
  KeyTab t{};
  for (int i = 0; i < NSTEPS; ++i) {
    uint32_t x0 = 0u, x1 = (uint32_t)i;
    threefry2x32(0u, 42u, x0, x1);
    t.a[i] = x0; t.b[i] = x1;
  }
  return t;
}
__device__ __constant__ KeyTab SKEYS = make_keys();

// XLA ErfInv chain-1, sqrt(2) pre-folded, packed pair. (damped path)
__device__ __forceinline__ v2f erfinv_p1_s2_v2(v2f w) {
  v2f ws = w - 2.5f;
  v2f p = splat(3.9742775e-08f);
  p = pfma(p, ws, splat(4.8546373e-07f));
  p = pfma(p, ws, splat(-4.9828418e-06f));
  p = pfma(p, ws, splat(-6.2105426e-06f));
  p = pfma(p, ws, splat(3.0912074e-04f));
  p = pfma(p, ws, splat(-1.7730442e-03f));
  p = pfma(p, ws, splat(-5.9081479e-03f));
  p = pfma(p, ws, splat(3.4880632e-01f));
  p = pfma(p, ws, splat(2.1233167e+00f));
  return p;
}
// chain-2 (w >= 5), sqrt(2)-folded, packed pair.
__device__ __forceinline__ v2f erfinv_p2_s2_v2(v2f w) {
  v2f wb = (v2f){__builtin_amdgcn_sqrtf(w.x) - 3.0f,
                 __builtin_amdgcn_sqrtf(w.y) - 3.0f};
  v2f p = splat(-2.8314768e-04f);
  p = pfma(p, wb, splat(1.4276574e-04f));
  p = pfma(p, wb, splat(1.9082629e-03f));
  p = pfma(p, wb, splat(-5.1950087e-03f));
  p = pfma(p, wb, splat(8.1169428e-03f));
  p = pfma(p, wb, splat(-1.0779867e-02f));
  p = pfma(p, wb, splat(1.3348557e-02f));
  p = pfma(p, wb, splat(1.4165801e+00f));
  p = pfma(p, wb, splat(4.0060855e+00f));
  return p;
}

__global__ __launch_bounds__(256)
void passive_layer_kernel(const float* __restrict__ xin,
                          const float* __restrict__ yin,
                          const float* __restrict__ zin,
                          const float* __restrict__ txin,
                          const float* __restrict__ tyin,
                          const float* __restrict__ momin,
                          const float* __restrict__ rad,
                          float* __restrict__ out, int N) {
  int n = blockIdx.x * blockDim.x + threadIdx.x;
  if (n >= N) return;

  float x = xin[n], y = yin[n], z = zin[n];
  float tx = txin[n], ty = tyin[n];
  float coef_over_p = COEF_A / momin[n];
  const uint32_t uN = (uint32_t)N;
  const uint32_t un = (uint32_t)n;
  const uint32_t c0a = un,      c1a = un + 2u * uN;
  const uint32_t c0b = un + uN, c1b = un + 3u * uN;

  // propagate to top of layer (position-critical: libm tanf).
  // These tan values are bit-identical to iteration 0's (tx,ty unchanged),
  // so they are shared with the loop body (R5b).
  float ttx = tanf(tx), tty = tanf(ty);
  float dz0 = z - Z_TOP;
  x += dz0 * ttx;
  y += dz0 * tty;
  z -= dz0;                                  // z == 1.0f exactly (Sterbenz)

  const float lo = -0.99999994f;             // nextafter(-1,0)
  const v2f lov = splat(lo);

#pragma unroll 1
  for (int i = 0;;) {
    bool mask = (z > Z_BOT);                 // z <= Z_TOP always true (R5c)
    // BIT-EXACT early exit: once z==Z_BOT (exact snap) the lane's body is a
    // no-op forever; when no lane is alive the loop ends.
    if (!__any(mask)) break;

    // Scattered gather first so latency hides under threefry/erfinv work.
    bool smask = (x >= 0.0f) && (x < LW) && (y >= 0.0f) && (y < LW) && mask;
    int ix = (int)floorf(x / VSIZE); ix = min(max(ix, 0), 99);  // exact divide
    int iy = (int)floorf(y / VSIZE); iy = min(max(iy, 0), 99);
    float x0 = rad[ix * 100 + iy];

    uint32_t k0 = SKEYS.a[i], k1 = SKEYS.b[i];   // wave-uniform scalar loads
    uint32_t a0 = c0a, a1 = c1a;
    threefry2x32(k0, k1, a0, a1);            // -> zr0, zr2
    uint32_t b0 = c0b, b1 = c1b;
    threefry2x32(k0, k1, b0, b1);            // -> zr1, zr3

    float s = 1.0f + ttx * ttx + tty * tty;  // position-critical shape
    float cos_th = rsqrtf(s);                // position-critical (dz)

    // theta0 path: damped by ~0.0136 -> hw transcendentals safe (R2-validated)
    float r_out = (z - Z_BOT) * __builtin_amdgcn_sqrtf(s);
    float step_len = fmaxf(fminf(STEP, r_out), 1e-9f);
    float n_x0 = step_len * __builtin_amdgcn_rcpf(x0);
    float theta0 = (coef_over_p * __builtin_amdgcn_sqrtf(n_x0))
                 * fmaf(COEF_B, __logf(n_x0), 1.0f);

    // normals, packed pairs: A=(z0,z1) [dtheta draws], B=(z2,z3) [dx draws]
    uint32_t fa0 = (a0 >> 9) | 0x3f800000u;
    uint32_t fb0 = (b0 >> 9) | 0x3f800000u;
    uint32_t fa1 = (a1 >> 9) | 0x3f800000u;
    uint32_t fb1 = (b1 >> 9) | 0x3f800000u;
    v2f bfA = (v2f){__uint_as_float(fa0), __uint_as_float(fb0)};
    v2f bfB = (v2f){__uint_as_float(fa1), __uint_as_float(fb1)};
    v2f fA = bfA - 1.0f;                     // [0,1)
    v2f fB = bfB - 1.0f;
    v2f uA = fA * 2.0f + lov;                // same shape as scalar R4
    v2f uB = fB * 2.0f + lov;
    uA = __builtin_elementwise_max(uA, lov);
    uB = __builtin_elementwise_max(uB, lov);
    v2f tA = pfma(uA, -uA, splat(1.0f));     // 1 - u^2 (exactly rounded)
    v2f tB = pfma(uB, -uB, splat(1.0f));
    v2f wA = (v2f){-__logf(tA.x), -__logf(tA.y)};
    v2f wB = (v2f){-__logf(tB.x), -__logf(tB.y)};
    v2f pA = erfinv_p1_s2_v2(wA);
    v2f pB = erfinv_p1_s2_v2(wB);
    if (__any((wA.x >= 5.0f) || (wA.y >= 5.0f))) {   // ~35% of waves
      v2f q = erfinv_p2_s2_v2(wA);
      pA.x = (wA.x < 5.0f) ? pA.x : q.x;
      pA.y = (wA.y < 5.0f) ? pA.y : q.y;
    }
    if (__any((wB.x >= 5.0f) || (wB.y >= 5.0f))) {   // ~35% of waves
      v2f q = erfinv_p2_s2_v2(wB);
      pB.x = (wB.x < 5.0f) ? pB.x : q.x;
      pB.y = (wB.y < 5.0f) ? pB.y : q.y;
    }
    v2f zA = pA * uA;                        // sqrt(2) folded; (z0, z1)
    v2f zB = pB * uB;                        // (z2, z3)

    v2f dt = splat(theta0) * zA;             // (dtx, dty)
    float slt = step_len * theta0;
    const float inv_s12 = 0.28867513459f;    // 1/sqrt(12), damped path
    v2f dv = splat(slt) * (zB * inv_s12 + zA * 0.5f);  // (dxv, dyv)

    // Position updates: scalar, expression shapes identical to R4.
    float dxvm = smask ? dv.x : 0.0f;
    float dyvm = smask ? dv.y : 0.0f;
    x += dxvm;
    y += dyvm;

    float dz  = STEP * cos_th;
    float dzm = mask ? dz : 0.0f;
    x += dzm * ttx;
    y += dzm * tty;
    z -= dzm;

    float dzr  = z - Z_BOT;
    bool  em   = (dzr < 0.0f) && mask;
    float dzrm = em ? dzr : 0.0f;
    x += dzrm * ttx;
    y += dzrm * tty;
    z -= dzrm;                               // exited lanes: z == Z_BOT exact

    float dtxm = smask ? dt.x : 0.0f;
    float dtym = smask ? dt.y : 0.0f;
    tx += dtxm;
    ty += dtym;

    ++i;
    if (i == NSTEPS) break;
    if (!__any(z > Z_BOT)) break;            // skip dead tan recompute (R5b)
    ttx = tanf(tx);                          // position-critical: libm
    tty = tanf(ty);
  }

  // Final snap deleted (R5a): dz1 = z - Z_BOT == 0.0f bitwise for every muon
  // (all exit via the Sterbenz-exact em pullback), so x += 0*tan is a no-op.

  float4 o = make_float4(x, y, tx, ty);
  reinterpret_cast<float4*>(out)[n] = o;
}

extern "C" void kernel_launch(void* const* d_in, const int* in_sizes, int n_in,
                              void* d_out, int out_size, void* d_ws, size_t ws_size,
                              hipStream_t stream) {
  const float* x   = (const float*)d_in[0];
  const float* y   = (const float*)d_in[1];
  const float* z   = (const float*)d_in[2];
  const float* tx  = (const float*)d_in[3];
  const float* ty  = (const float*)d_in[4];
  const float* mom = (const float*)d_in[5];
  const float* rad = (const float*)d_in[6];
  float* out = (float*)d_out;
  int N = in_sizes[0];
  int block = 256;
  int grid = (N + block - 1) / block;
  passive_layer_kernel<<<grid, block, 0, stream>>>(x, y, z, tx, ty, mom, rad, out, N);
}